// Round 8
// baseline (2307.985 us; speedup 1.0000x reference)
//
#include <hip/hip_runtime.h>

#define R 116
#define BATCH 1024
#define NL 4
#define RR2 13456          // R*R
#define EPSF 1e-5f
#define NZ_ELEM (BATCH * RR2)     // 13,778,944
#define NX_ELEM (BATCH * R * 3)   //    356,352
#define LS 136                    // LDS row stride (bf16 elems); 17 chunks of 8 (odd -> bank skew)
#define XZS 2336                  // XZ/cw1p K-stride: 2320 padded to 73*32

typedef unsigned short ushort_t;
typedef __attribute__((ext_vector_type(8))) short bf16x8;
typedef __attribute__((ext_vector_type(4))) float f32x4;

__device__ __forceinline__ float bf2f(unsigned short u){
  union { unsigned int i; float f; } v; v.i = ((unsigned int)u) << 16; return v.f;
}
__device__ __forceinline__ unsigned short f2bf(float f){
  union { float ff; unsigned int i; } v; v.ff = f;
  return (unsigned short)((v.i + 0x7fffu + ((v.i >> 16) & 1u)) >> 16);
}
__device__ __forceinline__ float wsum(float v){
  #pragma unroll
  for (int o = 32; o > 0; o >>= 1) v += __shfl_xor(v, o, 64);
  return v;
}
__device__ __forceinline__ float wmaxr(float v){
  #pragma unroll
  for (int o = 32; o > 0; o >>= 1) v = fmaxf(v, __shfl_xor(v, o, 64));
  return v;
}

// ---------------- init: Z fp32 -> bf16 ----------------
__global__ void k_initZ(const float4* __restrict__ src, uint4* __restrict__ dst, int n8){
  int idx = blockIdx.x * blockDim.x + threadIdx.x;
  int stride = gridDim.x * blockDim.x;
  for (int i = idx; i < n8; i += stride){
    float4 a = src[2*i], b = src[2*i+1];
    uint4 w;
    w.x = (unsigned)f2bf(a.x) | ((unsigned)f2bf(a.y) << 16);
    w.y = (unsigned)f2bf(a.z) | ((unsigned)f2bf(a.w) << 16);
    w.z = (unsigned)f2bf(b.x) | ((unsigned)f2bf(b.y) << 16);
    w.w = (unsigned)f2bf(b.z) | ((unsigned)f2bf(b.w) << 16);
    dst[i] = w;
  }
}

// ---------------- init: copy X fp32, zero stats, zero XZ ----------------
__global__ void k_initX(const float* __restrict__ src, float* __restrict__ dst, int n,
                        float* __restrict__ stats, int nstats,
                        unsigned* __restrict__ xzw, int nxzw){
  int idx = blockIdx.x * blockDim.x + threadIdx.x;
  int stride = gridDim.x * blockDim.x;
  for (int i = idx; i < n; i += stride) dst[i] = src[i];
  for (int i = idx; i < nstats; i += stride) stats[i] = 0.f;
  for (int i = idx; i < nxzw; i += stride) xzw[i] = 0u;
}

// ---------------- init: pack aw2^T / ew for MFMA B-operand (128x128, bf16) ----------------
__global__ void k_initW(const float* __restrict__ aw2, const float* __restrict__ ew,
                        ushort_t* __restrict__ aw2p, ushort_t* __restrict__ ewp){
  int idx = blockIdx.x * 256 + threadIdx.x;   // 4*128*128
  int l = idx >> 14, rem = idx & 16383, row = rem >> 7, col = rem & 127;
  ushort_t v = 0, w = 0;
  if (row < R && col < R){
    v = f2bf(aw2[l*RR2 + col*R + row]);   // aw2[k=col][c=row]
    w = f2bf(ew [l*RR2 + row*R + col]);   // ew[e=row][c=col]
  }
  aw2p[idx] = v;
  ewp [idx] = w;
}

// ---------------- init: pack cw1 -> bf16 [n][k], K padded to XZS ----------------
__global__ void k_initC(const float* __restrict__ cw1, ushort_t* __restrict__ cw1p){
  int idx = blockIdx.x * 256 + threadIdx.x;
  if (idx >= 1024 * XZS) return;
  int n = idx / XZS, k = idx - n * XZS;
  cw1p[idx] = (k < 2320) ? f2bf(cw1[n*2320 + k]) : (ushort_t)0;
}

// ---------------- MFMA attention + edge/node update + fused BN stats ----------------
__launch_bounds__(1024)
__global__ void k_attn(const float* __restrict__ Xc, const ushort_t* __restrict__ Zc,
                       ushort_t* __restrict__ Z1, float* __restrict__ X1,
                       const float* __restrict__ aw1, const float* __restrict__ ab1,
                       const ushort_t* __restrict__ aw2p, const float* __restrict__ ab2,
                       const float* __restrict__ nw,  const float* __restrict__ nb,
                       const ushort_t* __restrict__ ewp,  const float* __restrict__ eb,
                       float* __restrict__ zsum, float* __restrict__ zsq,
                       float* __restrict__ xsum, float* __restrict__ xsq, int layer)
{
  __shared__ ushort_t Zl [128*LS];   // Z row-major
  __shared__ ushort_t ZTl[128*LS];   // Z^T row-major
  __shared__ ushort_t bA [128*LS];   // P, then M
  __shared__ ushort_t bB [128*LS];   // W, then T1
  __shared__ float Ksm[3*R];
  __shared__ float ssm[R];
  __shared__ float xp[R*12];         // X-path partials [n][part][c]

  const int b    = blockIdx.x;
  const int tid  = threadIdx.x;
  const int lane = tid & 63;
  const int wave = tid >> 6;          // 16 waves
  const int qm   = lane & 15;
  const int quad = lane >> 4;
  const int tr   = wave & 7;
  const int tc0  = (wave >> 3) * 4;

  const float*    Xb = Xc + (size_t)b * R * 3;
  const ushort_t* Zb = Zc + (size_t)b * RR2;
  const ushort_t* aw2l = aw2p + layer * 16384;
  const ushort_t* ewl  = ewp  + layer * 16384;
  const float* aw1l = aw1 + layer * 9;
  const float* ab1l = ab1 + layer * 3;
  const float* ab2l = ab2 + layer * R;
  const float* ebl  = eb  + layer * R;
  const float* nwl  = nw  + layer * 9;
  const float* nbl  = nb  + layer * 3;

  const f32x4 vzero = {0.f, 0.f, 0.f, 0.f};

  // phase 0: zero only pad strips (rows 116-127 full; cols 116-135 of rows <116)
  for (int i = tid; i < 12*LS; i += 1024){
    Zl[116*LS+i]=0; ZTl[116*LS+i]=0; bA[116*LS+i]=0; bB[116*LS+i]=0;
  }
  for (int i = tid; i < 116*20; i += 1024){
    int r = i/20, c = 116 + (i - r*20);
    Zl[r*LS+c]=0; ZTl[r*LS+c]=0; bA[r*LS+c]=0; bB[r*LS+c]=0;
  }
  // K[o][n]
  if (tid < R){
    float x0 = Xb[tid*3+0], x1 = Xb[tid*3+1], x2 = Xb[tid*3+2];
    #pragma unroll
    for (int o = 0; o < 3; o++)
      Ksm[o*R + tid] = ab1l[o] + aw1l[o*3+0]*x0 + aw1l[o*3+1]*x1 + aw1l[o*3+2]*x2;
  }
  // phase 1a: stage Z rows (vectorized 8B)
  for (int task = tid; task < 116*29; task += 1024){
    int rr = task / 29, c4 = task - rr*29;
    ushort4 z4 = ((const ushort4*)(Zb + rr*R))[c4];
    *(ushort4*)&Zl[rr*LS + c4*4] = z4;
  }
  __syncthreads();

  // phase 1b: transpose Zl -> ZTl (b128 row reads, conflict-free column writes)
  for (int task = tid; task < 128*15; task += 1024){
    int m = task & 127, c8 = task >> 7;     // consecutive lanes -> consecutive m
    bf16x8 v = *(const bf16x8*)&Zl[m*LS + c8*8];
    #pragma unroll
    for (int t2 = 0; t2 < 8; t2++)
      ZTl[(c8*8 + t2)*LS + m] = (ushort_t)v[t2];
  }
  // softmax rows -> bA
  for (int n = wave; n < R; n += 16){
    float k0 = Ksm[n], k1 = Ksm[R+n], k2 = Ksm[2*R+n];
    int m0 = lane, m1 = lane + 64;
    float a0 = k0*Ksm[m0] + k1*Ksm[R+m0] + k2*Ksm[2*R+m0];
    float a1 = (m1 < R) ? (k0*Ksm[m1] + k1*Ksm[R+m1] + k2*Ksm[2*R+m1]) : -1e30f;
    float mx = wmaxr(fmaxf(a0, a1));
    float e0 = __expf(a0 - mx);
    float e1 = (m1 < R) ? __expf(a1 - mx) : 0.f;
    float sm = wsum(e0 + e1);
    float sab = wsum(e0 * ab2l[m0] + ((m1 < R) ? e1 * ab2l[m1] : 0.f));
    float inv = 1.f / sm;
    bA[n*LS + m0] = f2bf(e0 * inv);
    if (m1 < R) bA[n*LS + m1] = f2bf(e1 * inv);
    if (lane == 0) ssm[n] = sab * inv;
  }
  __syncthreads();

  // ---- Stage A: W = P @ aw2 -> bB ----
  {
    f32x4 acc[4];
    #pragma unroll
    for (int t = 0; t < 4; t++) acc[t] = vzero;
    for (int kk = 0; kk < 128; kk += 32){
      bf16x8 a = *(const bf16x8*)&bA[(tr*16 + qm)*LS + kk + quad*8];
      #pragma unroll
      for (int t = 0; t < 4; t++){
        int n = (tc0 + t)*16 + qm;
        bf16x8 bf = *(const bf16x8*)(aw2l + n*128 + kk + quad*8);
        acc[t] = __builtin_amdgcn_mfma_f32_16x16x32_bf16(a, bf, acc[t], 0, 0, 0);
      }
    }
    #pragma unroll
    for (int t = 0; t < 4; t++){
      int n = (tc0 + t)*16 + qm;
      #pragma unroll
      for (int rg = 0; rg < 4; rg++)
        bB[(tr*16 + quad*4 + rg)*LS + n] = f2bf(acc[t][rg]);
    }
  }
  __syncthreads();

  // ---- Stage B: M = Z @ W^T + ssm -> bA ----
  {
    f32x4 acc[4];
    #pragma unroll
    for (int t = 0; t < 4; t++) acc[t] = vzero;
    for (int kk = 0; kk < 128; kk += 32){
      bf16x8 a = *(const bf16x8*)&Zl[(tr*16 + qm)*LS + kk + quad*8];
      #pragma unroll
      for (int t = 0; t < 4; t++){
        int n = (tc0 + t)*16 + qm;
        bf16x8 bf = *(const bf16x8*)&bB[n*LS + kk + quad*8];
        acc[t] = __builtin_amdgcn_mfma_f32_16x16x32_bf16(a, bf, acc[t], 0, 0, 0);
      }
    }
    #pragma unroll
    for (int t = 0; t < 4; t++){
      int n = (tc0 + t)*16 + qm;
      float sadd = (n < R) ? ssm[n] : 0.f;
      #pragma unroll
      for (int rg = 0; rg < 4; rg++)
        bA[(tr*16 + quad*4 + rg)*LS + n] = f2bf(acc[t][rg] + sadd);
    }
  }
  __syncthreads();

  // ---- Stage C: T1 = M @ Z -> bB ----
  {
    f32x4 acc[4];
    #pragma unroll
    for (int t = 0; t < 4; t++) acc[t] = vzero;
    for (int kk = 0; kk < 128; kk += 32){
      bf16x8 a = *(const bf16x8*)&bA[(tr*16 + qm)*LS + kk + quad*8];
      #pragma unroll
      for (int t = 0; t < 4; t++){
        int n = (tc0 + t)*16 + qm;
        bf16x8 bf = *(const bf16x8*)&ZTl[n*LS + kk + quad*8];
        acc[t] = __builtin_amdgcn_mfma_f32_16x16x32_bf16(a, bf, acc[t], 0, 0, 0);
      }
    }
    #pragma unroll
    for (int t = 0; t < 4; t++){
      int n = (tc0 + t)*16 + qm;
      #pragma unroll
      for (int rg = 0; rg < 4; rg++)
        bB[(tr*16 + quad*4 + rg)*LS + n] = f2bf(acc[t][rg]);
    }
  }
  __syncthreads();

  // ---- Stage D: Z1 = T1 @ ew^T + eb -> global bf16, fused Z-BN stats ----
  {
    f32x4 acc[4];
    #pragma unroll
    for (int t = 0; t < 4; t++) acc[t] = vzero;
    for (int kk = 0; kk < 128; kk += 32){
      bf16x8 a = *(const bf16x8*)&bB[(tr*16 + qm)*LS + kk + quad*8];
      #pragma unroll
      for (int t = 0; t < 4; t++){
        int n = (tc0 + t)*16 + qm;
        bf16x8 bf = *(const bf16x8*)(ewl + n*128 + kk + quad*8);
        acc[t] = __builtin_amdgcn_mfma_f32_16x16x32_bf16(a, bf, acc[t], 0, 0, 0);
      }
    }
    float ssv[4] = {0.f,0.f,0.f,0.f}, sqv[4] = {0.f,0.f,0.f,0.f};
    #pragma unroll
    for (int t = 0; t < 4; t++){
      int col = (tc0 + t)*16 + qm;
      float bias = (col < R) ? ebl[col] : 0.f;
      #pragma unroll
      for (int rg = 0; rg < 4; rg++){
        int row = tr*16 + quad*4 + rg;
        float v = (col < R) ? (acc[t][rg] + bias) : 0.f;
        if (col < R && row < R)
          Z1[(size_t)b*RR2 + row*R + col] = f2bf(v);
        ssv[rg] += v; sqv[rg] += v*v;
      }
    }
    #pragma unroll
    for (int off = 1; off < 16; off <<= 1){
      #pragma unroll
      for (int rg = 0; rg < 4; rg++){
        ssv[rg] += __shfl_xor(ssv[rg], off, 64);
        sqv[rg] += __shfl_xor(sqv[rg], off, 64);
      }
    }
    if (qm == 0){
      #pragma unroll
      for (int rg = 0; rg < 4; rg++){
        int row = tr*16 + quad*4 + rg;
        if (row < R){
          atomicAdd(&zsum[layer*R + row], ssv[rg]);
          atomicAdd(&zsq [layer*R + row], sqv[rg]);
        }
      }
    }
  }

  // ---- X path partials: T1x = M @ X (M stable in bA) ----
  if (tid < R*4){
    int n = tid >> 2, part = tid & 3;
    float t0 = 0.f, t1 = 0.f, t2 = 0.f;
    for (int m = part; m < R; m += 4){
      float p = bf2f(bA[n*LS + m]);
      const float* xr = Xb + m*3;
      t0 += p*xr[0]; t1 += p*xr[1]; t2 += p*xr[2];
    }
    xp[tid*3+0] = t0; xp[tid*3+1] = t1; xp[tid*3+2] = t2;
  }
  __syncthreads();
  if (tid < R){
    float c0 = xp[tid*12+0] + xp[tid*12+3] + xp[tid*12+6] + xp[tid*12+9];
    float c1 = xp[tid*12+1] + xp[tid*12+4] + xp[tid*12+7] + xp[tid*12+10];
    float c2 = xp[tid*12+2] + xp[tid*12+5] + xp[tid*12+8] + xp[tid*12+11];
    float s = 0.f, q = 0.f;
    #pragma unroll
    for (int e = 0; e < 3; e++){
      float v = nbl[e] + c0*nwl[e*3+0] + c1*nwl[e*3+1] + c2*nwl[e*3+2];
      X1[((size_t)b*R + tid)*3 + e] = v;
      s += v; q += v*v;
    }
    atomicAdd(&xsum[layer*R + tid], s);
    atomicAdd(&xsq [layer*R + tid], q);
  }
}

// ---------------- fused: BN+relu+residual on Z, then edge downsample ----------------
__launch_bounds__(256)
__global__ void k_bnzde(const ushort_t* __restrict__ Z1, ushort_t* __restrict__ Zc,
                        const float* __restrict__ zsum, const float* __restrict__ zsq,
                        const float* __restrict__ geg, const float* __restrict__ geb,
                        const float* __restrict__ dew, const float* __restrict__ deb,
                        ushort_t* __restrict__ XZ, float* __restrict__ deS, int layer)
{
  __shared__ float rb[64*121];
  __shared__ float wsm[78];
  __shared__ float reds[4], redq[4];
  const int tid = threadIdx.x;
  const int gr0 = blockIdx.x * 64;
  const int t = layer + 1;
  if (tid < 78) wsm[tid] = dew[t*78 + tid];
  const int row = tid >> 2, part = tid & 3;
  const int gr = gr0 + row;
  const int n = gr % R;
  const float cnt = (float)(BATCH * R);
  float m  = zsum[layer*R + n] / cnt;
  float va = fmaxf(zsq[layer*R + n] / cnt - m*m, 0.f);
  float rs = rsqrtf(va + EPSF);
  float g  = geg[layer*R + n], be = geb[layer*R + n];
  const ushort_t* z1r = Z1 + (size_t)gr * R;
  ushort_t* zcr = Zc + (size_t)gr * R;
  #pragma unroll 4
  for (int i = 0; i < 29; i++){
    int c = part*29 + i;
    float val = fmaxf((bf2f(z1r[c]) - m)*rs*g + be, 0.f) + bf2f(zcr[c]);
    zcr[c] = f2bf(val);
    rb[row*121 + c] = val;
  }
  __syncthreads();
  // conv: part p output f_p = sum_j w[j]*row[j + 39(p-1)], valid j ranges
  int jlo = (part == 0) ? 39 : 0;
  int jhi = (part == 2) ? 77 : 78;
  if (part == 3){ jlo = 0; jhi = 0; }
  int off = (part - 1) * 39;
  float f = 0.f;
  for (int j = jlo; j < jhi; j++) f += wsm[j] * rb[row*121 + j + off];
  float s = 0.f, q = 0.f;
  if (part < 3){
    f = fmaxf(f + deb[t], 0.f);
    int bi = gr / R, r = gr - bi*R;
    XZ[(size_t)bi*XZS + 5*R + t*3*R + r*3 + part] = f2bf(f);   // pre-BN feat in place
    s = f; q = f*f;
  }
  s = wsum(s); q = wsum(q);
  int lane = tid & 63, wv = tid >> 6;
  if (lane == 0){ reds[wv] = s; redq[wv] = q; }
  __syncthreads();
  if (tid == 0){
    atomicAdd(&deS[t*2+0], reds[0]+reds[1]+reds[2]+reds[3]);
    atomicAdd(&deS[t*2+1], redq[0]+redq[1]+redq[2]+redq[3]);
  }
}

// ---------------- fused: BN+relu+residual on X, then node downsample ----------------
__global__ void k_bnxdn(const float* __restrict__ X1, float* __restrict__ Xc,
                        const float* __restrict__ xsum, const float* __restrict__ xsq,
                        const float* __restrict__ gng, const float* __restrict__ gnb,
                        const float* __restrict__ dnw, const float* __restrict__ dnb,
                        ushort_t* __restrict__ XZ, float* __restrict__ dnS, int layer)
{
  int idx = blockIdx.x * 256 + threadIdx.x;    // BATCH*R
  int n = idx % R;
  const int t = layer + 1;
  const float cnt = (float)(BATCH * 3);
  float m  = xsum[layer*R + n] / cnt;
  float va = fmaxf(xsq[layer*R + n] / cnt - m*m, 0.f);
  float rs = rsqrtf(va + EPSF);
  float g  = gng[layer*R + n], be = gnb[layer*R + n];
  float v[3];
  #pragma unroll
  for (int c = 0; c < 3; c++){
    float x = (X1[idx*3 + c] - m)*rs*g + be;
    v[c] = fmaxf(x, 0.f) + Xc[idx*3 + c];
    Xc[idx*3 + c] = v[c];
  }
  float f = fmaxf(dnw[t*3+0]*v[0] + dnw[t*3+1]*v[1] + dnw[t*3+2]*v[2] + dnb[t], 0.f);
  int bi = idx / R, r = idx - bi*R;
  XZ[(size_t)bi*XZS + t*R + r] = f2bf(f);
  float s = wsum(f), q = wsum(f*f);
  __shared__ float s1[4], s2[4];
  int lane = threadIdx.x & 63, wv = threadIdx.x >> 6;
  if (lane == 0){ s1[wv] = s; s2[wv] = q; }
  __syncthreads();
  if (threadIdx.x == 0){
    atomicAdd(&dnS[t*2+0], s1[0]+s1[1]+s1[2]+s1[3]);
    atomicAdd(&dnS[t*2+1], s2[0]+s2[1]+s2[2]+s2[3]);
  }
}

// ---------------- t=0 node downsample (reads Xc, stats + pre-BN feat) ----------------
__global__ void k_dnode0(const float* __restrict__ Xc, const float* __restrict__ dnw,
                         const float* __restrict__ dnb, ushort_t* __restrict__ XZ,
                         float* __restrict__ dnS){
  int idx = blockIdx.x * 256 + threadIdx.x;    // BATCH*R
  float f = fmaxf(dnw[0]*Xc[idx*3] + dnw[1]*Xc[idx*3+1] + dnw[2]*Xc[idx*3+2] + dnb[0], 0.f);
  int bi = idx / R, r = idx - bi*R;
  XZ[(size_t)bi*XZS + r] = f2bf(f);
  float s = wsum(f), q = wsum(f*f);
  __shared__ float s1[4], s2[4];
  int lane = threadIdx.x & 63, wv = threadIdx.x >> 6;
  if (lane == 0){ s1[wv] = s; s2[wv] = q; }
  __syncthreads();
  if (threadIdx.x == 0){
    atomicAdd(&dnS[0], s1[0]+s1[1]+s1[2]+s1[3]);
    atomicAdd(&dnS[1], s2[0]+s2[1]+s2[2]+s2[3]);
  }
}

// ---------------- t=0 edge downsample (reads Zc) ----------------
__global__ void k_dedge0(const ushort_t* __restrict__ Zc, const float* __restrict__ dew,
                         const float* __restrict__ deb, ushort_t* __restrict__ XZ,
                         float* __restrict__ deS){
  __shared__ float wsm[78];
  if (threadIdx.x < 78) wsm[threadIdx.x] = dew[threadIdx.x];
  __syncthreads();
  int idx = blockIdx.x * 256 + threadIdx.x;    // BATCH*R
  const ushort_t* x = Zc + (size_t)idx * R;
  float bb = deb[0];
  float f0 = 0.f, f1 = 0.f, f2 = 0.f;
  for (int j = 0; j < 78; j++){
    float w = wsm[j];
    if (j >= 39) f0 += w * bf2f(x[j - 39]);
    f1 += w * bf2f(x[j]);
    if (j < 77)  f2 += w * bf2f(x[j + 39]);
  }
  f0 = fmaxf(f0 + bb, 0.f); f1 = fmaxf(f1 + bb, 0.f); f2 = fmaxf(f2 + bb, 0.f);
  int bi = idx / R, r = idx - bi*R;
  size_t base = (size_t)bi*XZS + 5*R + r*3;
  XZ[base+0] = f2bf(f0); XZ[base+1] = f2bf(f1); XZ[base+2] = f2bf(f2);
  float s = wsum(f0+f1+f2), q = wsum(f0*f0+f1*f1+f2*f2);
  __shared__ float s1[4], s2[4];
  int lane = threadIdx.x & 63, wv = threadIdx.x >> 6;
  if (lane == 0){ s1[wv] = s; s2[wv] = q; }
  __syncthreads();
  if (threadIdx.x == 0){
    atomicAdd(&deS[0], s1[0]+s1[1]+s1[2]+s1[3]);
    atomicAdd(&deS[1], s2[0]+s2[1]+s2[2]+s2[3]);
  }
}

// ---------------- apply BN (in place) to XZ feature slots for snapshot t ----------------
__global__ void k_apply(const float* __restrict__ dnS, const float* __restrict__ deS,
                        const float* __restrict__ dng, const float* __restrict__ dnbe,
                        const float* __restrict__ deg, const float* __restrict__ debe,
                        ushort_t* __restrict__ XZ, int t)
{
  int idx = blockIdx.x * 256 + threadIdx.x;    // BATCH*R
  int bi = idx / R, r = idx - bi*R;
  const float cn = (float)(BATCH * R);
  float mn = dnS[t*2+0] / cn;
  float vn = fmaxf(dnS[t*2+1] / cn - mn*mn, 0.f);
  size_t sn = (size_t)bi*XZS + t*R + r;
  float hn = (bf2f(XZ[sn]) - mn) * rsqrtf(vn + EPSF) * dng[t] + dnbe[t];
  XZ[sn] = f2bf(hn);
  const float ce = (float)(BATCH * R * 3);
  float me = deS[t*2+0] / ce;
  float ve = fmaxf(deS[t*2+1] / ce - me*me, 0.f);
  float rse = rsqrtf(ve + EPSF);
  size_t se = (size_t)bi*XZS + 5*R + t*3*R + r*3;
  #pragma unroll
  for (int p = 0; p < 3; p++){
    float he = (bf2f(XZ[se+p]) - me) * rse * deg[t] + debe[t];
    XZ[se+p] = f2bf(he);
  }
}

// ---------------- classifier: fc1 bf16 MFMA GEMM ----------------
__launch_bounds__(256)
__global__ void k_fc1(const ushort_t* __restrict__ XZ, const ushort_t* __restrict__ cw1p,
                      const float* __restrict__ cb1, float* __restrict__ H){
  const int tid  = threadIdx.x;
  const int lane = tid & 63;
  const int wave = tid >> 6;
  const int qm   = lane & 15;
  const int quad = lane >> 4;
  const int m0   = blockIdx.x * 64 + wave * 16;
  const int n0   = blockIdx.y * 64;

  const f32x4 vzero = {0.f, 0.f, 0.f, 0.f};
  f32x4 acc[4];
  #pragma unroll
  for (int t = 0; t < 4; t++) acc[t] = vzero;

  const ushort_t* arow = XZ + (size_t)(m0 + qm) * XZS;
  for (int kk = 0; kk < XZS; kk += 32){
    bf16x8 a = *(const bf16x8*)(arow + kk + quad*8);
    #pragma unroll
    for (int t = 0; t < 4; t++){
      const ushort_t* brow = cw1p + (size_t)(n0 + t*16 + qm) * XZS;
      bf16x8 bf = *(const bf16x8*)(brow + kk + quad*8);
      acc[t] = __builtin_amdgcn_mfma_f32_16x16x32_bf16(a, bf, acc[t], 0, 0, 0);
    }
  }
  #pragma unroll
  for (int t = 0; t < 4; t++){
    int n = n0 + t*16 + qm;
    float bias = cb1[n];
    #pragma unroll
    for (int rg = 0; rg < 4; rg++){
      int m = m0 + quad*4 + rg;
      H[(size_t)m * 1024 + n] = fmaxf(acc[t][rg] + bias, 0.f);
    }
  }
}

__global__ void k_fc2(const float* __restrict__ H, const float* __restrict__ cw2,
                      const float* __restrict__ cb2, float* __restrict__ out){
  int b = blockIdx.x, tid = threadIdx.x;
  float a0 = 0.f, a1 = 0.f;
  for (int j = tid; j < 1024; j += 256){
    float h = H[(size_t)b * 1024 + j];
    a0 += h * cw2[j];
    a1 += h * cw2[1024 + j];
  }
  a0 = wsum(a0); a1 = wsum(a1);
  __shared__ float s0[4], s1[4];
  int lane = tid & 63, wave = tid >> 6;
  if (lane == 0){ s0[wave] = a0; s1[wave] = a1; }
  __syncthreads();
  if (tid == 0){
    out[b*2 + 0] = s0[0]+s0[1]+s0[2]+s0[3] + cb2[0];
    out[b*2 + 1] = s1[0]+s1[1]+s1[2]+s1[3] + cb2[1];
  }
}

extern "C" void kernel_launch(void* const* d_in, const int* in_sizes, int n_in,
                              void* d_out, int out_size, void* d_ws, size_t ws_size,
                              hipStream_t stream)
{
  const float* Xin  = (const float*)d_in[0];
  const float* Zin  = (const float*)d_in[1];
  const float* aw1  = (const float*)d_in[2];
  const float* ab1  = (const float*)d_in[3];
  const float* aw2  = (const float*)d_in[4];
  const float* ab2  = (const float*)d_in[5];
  const float* nw   = (const float*)d_in[6];
  const float* nb   = (const float*)d_in[7];
  const float* ew   = (const float*)d_in[8];
  const float* eb   = (const float*)d_in[9];
  const float* gng  = (const float*)d_in[10];
  const float* gnb  = (const float*)d_in[11];
  const float* geg  = (const float*)d_in[12];
  const float* geb  = (const float*)d_in[13];
  const float* dnw  = (const float*)d_in[14];
  const float* dnb  = (const float*)d_in[15];
  const float* dng  = (const float*)d_in[16];
  const float* dnbe = (const float*)d_in[17];
  const float* dew  = (const float*)d_in[18];
  const float* deb  = (const float*)d_in[19];
  const float* deg  = (const float*)d_in[20];
  const float* debe = (const float*)d_in[21];
  const float* cw1  = (const float*)d_in[22];
  const float* cb1  = (const float*)d_in[23];
  const float* cw2  = (const float*)d_in[24];
  const float* cb2  = (const float*)d_in[25];

  // ---- workspace layout: TOTAL 67,805,184 B (identical to R7-proven size) ----
  ushort_t* Zc = (ushort_t*)d_ws;            // bf16 Z state
  ushort_t* Z1 = Zc + NZ_ELEM;               // bf16 pre-BN Z1
  float*    H  = (float*)Z1;                 //   overlay: fc1 out (Z1 dead at fc1)
  float*    Xc = (float*)(Z1 + NZ_ELEM);     // fp32 X state
  float*    X1 = Xc + NX_ELEM;               // fp32 pre-BN X1
  ushort_t* XZ = (ushort_t*)(X1 + NX_ELEM);  // bf16 features (B,XZS)
  float*    st = (float*)(XZ + BATCH*XZS);   // stats: 2048 floats
  ushort_t* aw2p = (ushort_t*)(st + 2048);
  ushort_t* ewp  = aw2p + 4*16384;
  ushort_t* cw1p = ewp + 4*16384;
  float* zsum = st;        float* zsq = st + 464;
  float* xsum = st + 928;  float* xsq = st + 1392;
  float* dnS  = st + 1856; float* deS = st + 1866;

  float* outp = (float*)d_out;

  // init
  k_initZ<<<2048, 256, 0, stream>>>((const float4*)Zin, (uint4*)Zc, NZ_ELEM / 8);
  k_initX<<<1392, 256, 0, stream>>>(Xin, Xc, NX_ELEM, st, 2048,
                                    (unsigned*)XZ, BATCH*XZS/2);
  k_initW<<<256, 256, 0, stream>>>(aw2, ew, aw2p, ewp);
  k_initC<<<9344, 256, 0, stream>>>(cw1, cw1p);

  // t = 0 snapshots (pre-BN feats into XZ, stats, then in-place BN)
  k_dnode0<<<464, 256, 0, stream>>>(Xc, dnw, dnb, XZ, dnS);
  k_dedge0<<<464, 256, 0, stream>>>(Zc, dew, deb, XZ, deS);
  k_apply<<<464, 256, 0, stream>>>(dnS, deS, dng, dnbe, deg, debe, XZ, 0);

  for (int i = 0; i < NL; i++){
    k_attn<<<BATCH, 1024, 0, stream>>>(Xc, Zc, Z1, X1, aw1, ab1, aw2p, ab2,
                                       nw, nb, ewp, eb, zsum, zsq, xsum, xsq, i);
    k_bnzde<<<1856, 256, 0, stream>>>(Z1, Zc, zsum, zsq, geg, geb,
                                      dew, deb, XZ, deS, i);
    k_bnxdn<<<464, 256, 0, stream>>>(X1, Xc, xsum, xsq, gng, gnb,
                                     dnw, dnb, XZ, dnS, i);
    k_apply<<<464, 256, 0, stream>>>(dnS, deS, dng, dnbe, deg, debe, XZ, i + 1);
  }

  k_fc1<<<dim3(16, 16), 256, 0, stream>>>(XZ, cw1p, cb1, H);
  k_fc2<<<BATCH, 256, 0, stream>>>(H, cw2, cb2, outp);
}

// Round 9
// 1215.055 us; speedup vs baseline: 1.8995x; 1.8995x over previous
//
#include <hip/hip_runtime.h>

#define R 116
#define BATCH 1024
#define NL 4
#define RR2 13456          // R*R
#define EPSF 1e-5f
#define NZ_ELEM (BATCH * RR2)     // 13,778,944
#define NX_ELEM (BATCH * R * 3)   //    356,352
#define LS 136                    // LDS row stride (bf16 elems); odd multiple of 8 -> bank skew
#define XZS 2336                  // XZ/cw1p K-stride: 2320 padded to 73*32
#define NSH 8                     // stat shards (atomic contention divider)
#define STL 464                   // NL*R stats stride

typedef unsigned short ushort_t;
typedef __attribute__((ext_vector_type(8))) short bf16x8;
typedef __attribute__((ext_vector_type(4))) float f32x4;

__device__ __forceinline__ float bf2f(unsigned short u){
  union { unsigned int i; float f; } v; v.i = ((unsigned int)u) << 16; return v.f;
}
__device__ __forceinline__ unsigned short f2bf(float f){
  union { float ff; unsigned int i; } v; v.ff = f;
  return (unsigned short)((v.i + 0x7fffu + ((v.i >> 16) & 1u)) >> 16);
}
__device__ __forceinline__ float wsum(float v){
  #pragma unroll
  for (int o = 32; o > 0; o >>= 1) v += __shfl_xor(v, o, 64);
  return v;
}
__device__ __forceinline__ float wmaxr(float v){
  #pragma unroll
  for (int o = 32; o > 0; o >>= 1) v = fmaxf(v, __shfl_xor(v, o, 64));
  return v;
}

// ---------------- init: Z fp32 -> bf16 ----------------
__global__ void k_initZ(const float4* __restrict__ src, uint4* __restrict__ dst, int n8){
  int idx = blockIdx.x * blockDim.x + threadIdx.x;
  int stride = gridDim.x * blockDim.x;
  for (int i = idx; i < n8; i += stride){
    float4 a = src[2*i], b = src[2*i+1];
    uint4 w;
    w.x = (unsigned)f2bf(a.x) | ((unsigned)f2bf(a.y) << 16);
    w.y = (unsigned)f2bf(a.z) | ((unsigned)f2bf(a.w) << 16);
    w.z = (unsigned)f2bf(b.x) | ((unsigned)f2bf(b.y) << 16);
    w.w = (unsigned)f2bf(b.z) | ((unsigned)f2bf(b.w) << 16);
    dst[i] = w;
  }
}

// ---------------- init: copy X fp32, zero stats, zero XZ ----------------
__global__ void k_initX(const float* __restrict__ src, float* __restrict__ dst, int n,
                        float* __restrict__ stats, int nstats,
                        unsigned* __restrict__ xzw, int nxzw){
  int idx = blockIdx.x * blockDim.x + threadIdx.x;
  int stride = gridDim.x * blockDim.x;
  for (int i = idx; i < n; i += stride) dst[i] = src[i];
  for (int i = idx; i < nstats; i += stride) stats[i] = 0.f;
  for (int i = idx; i < nxzw; i += stride) xzw[i] = 0u;
}

// ---------------- init: pack aw2^T / ew for MFMA B-operand (128x128, bf16) ----------------
__global__ void k_initW(const float* __restrict__ aw2, const float* __restrict__ ew,
                        ushort_t* __restrict__ aw2p, ushort_t* __restrict__ ewp){
  int idx = blockIdx.x * 256 + threadIdx.x;   // 4*128*128
  int l = idx >> 14, rem = idx & 16383, row = rem >> 7, col = rem & 127;
  ushort_t v = 0, w = 0;
  if (row < R && col < R){
    v = f2bf(aw2[l*RR2 + col*R + row]);   // aw2[k=col][c=row]
    w = f2bf(ew [l*RR2 + row*R + col]);   // ew[e=row][c=col]
  }
  aw2p[idx] = v;
  ewp [idx] = w;
}

// ---------------- init: pack cw1 -> bf16 [n][k], K padded to XZS ----------------
__global__ void k_initC(const float* __restrict__ cw1, ushort_t* __restrict__ cw1p){
  int idx = blockIdx.x * 256 + threadIdx.x;
  if (idx >= 1024 * XZS) return;
  int n = idx / XZS, k = idx - n * XZS;
  cw1p[idx] = (k < 2320) ? f2bf(cw1[n*2320 + k]) : (ushort_t)0;
}

// ---------------- MFMA attention + edge/node update + block-reduced sharded BN stats ----------------
__launch_bounds__(1024)
__global__ void k_attn(const float* __restrict__ Xc, const ushort_t* __restrict__ Zc,
                       ushort_t* __restrict__ Z1, float* __restrict__ X1,
                       const float* __restrict__ aw1, const float* __restrict__ ab1,
                       const ushort_t* __restrict__ aw2p, const float* __restrict__ ab2,
                       const float* __restrict__ nw,  const float* __restrict__ nb,
                       const ushort_t* __restrict__ ewp,  const float* __restrict__ eb,
                       float* __restrict__ zsumS, float* __restrict__ zsqS,
                       float* __restrict__ xsumS, float* __restrict__ xsqS, int layer)
{
  __shared__ ushort_t Zl [128*LS];   // Z row-major
  __shared__ ushort_t ZTl[128*LS];   // Z^T row-major
  __shared__ ushort_t bA [128*LS];   // P, then M
  __shared__ ushort_t bB [128*LS];   // W, then T1
  __shared__ float Ksm[3*R];
  __shared__ float ssm[R];
  __shared__ float xp[R*12];         // X-path partials [n][part][c]
  __shared__ float zps[128*2];       // per-row Z1 sum partials (2 col-halves)
  __shared__ float zpq[128*2];       // per-row Z1 sq partials

  const int b    = blockIdx.x;
  const int tid  = threadIdx.x;
  const int lane = tid & 63;
  const int wave = tid >> 6;          // 16 waves
  const int qm   = lane & 15;
  const int quad = lane >> 4;
  const int tr   = wave & 7;
  const int tc0  = (wave >> 3) * 4;

  const float*    Xb = Xc + (size_t)b * R * 3;
  const ushort_t* Zb = Zc + (size_t)b * RR2;
  const ushort_t* aw2l = aw2p + layer * 16384;
  const ushort_t* ewl  = ewp  + layer * 16384;
  const float* aw1l = aw1 + layer * 9;
  const float* ab1l = ab1 + layer * 3;
  const float* ab2l = ab2 + layer * R;
  const float* ebl  = eb  + layer * R;
  const float* nwl  = nw  + layer * 9;
  const float* nbl  = nb  + layer * 3;

  const f32x4 vzero = {0.f, 0.f, 0.f, 0.f};

  // phase 0: zero only pad strips (rows 116-127 full; cols 116-135 of rows <116)
  for (int i = tid; i < 12*LS; i += 1024){
    Zl[116*LS+i]=0; ZTl[116*LS+i]=0; bA[116*LS+i]=0; bB[116*LS+i]=0;
  }
  for (int i = tid; i < 116*20; i += 1024){
    int r = i/20, c = 116 + (i - r*20);
    Zl[r*LS+c]=0; ZTl[r*LS+c]=0; bA[r*LS+c]=0; bB[r*LS+c]=0;
  }
  // K[o][n]
  if (tid < R){
    float x0 = Xb[tid*3+0], x1 = Xb[tid*3+1], x2 = Xb[tid*3+2];
    #pragma unroll
    for (int o = 0; o < 3; o++)
      Ksm[o*R + tid] = ab1l[o] + aw1l[o*3+0]*x0 + aw1l[o*3+1]*x1 + aw1l[o*3+2]*x2;
  }
  // phase 1a: stage Z rows (vectorized 8B)
  for (int task = tid; task < 116*29; task += 1024){
    int rr = task / 29, c4 = task - rr*29;
    ushort4 z4 = ((const ushort4*)(Zb + rr*R))[c4];
    *(ushort4*)&Zl[rr*LS + c4*4] = z4;
  }
  __syncthreads();

  // phase 1b: transpose Zl -> ZTl
  for (int task = tid; task < 128*15; task += 1024){
    int m = task & 127, c8 = task >> 7;
    bf16x8 v = *(const bf16x8*)&Zl[m*LS + c8*8];
    #pragma unroll
    for (int t2 = 0; t2 < 8; t2++)
      ZTl[(c8*8 + t2)*LS + m] = (ushort_t)v[t2];
  }
  // softmax rows -> bA
  for (int n = wave; n < R; n += 16){
    float k0 = Ksm[n], k1 = Ksm[R+n], k2 = Ksm[2*R+n];
    int m0 = lane, m1 = lane + 64;
    float a0 = k0*Ksm[m0] + k1*Ksm[R+m0] + k2*Ksm[2*R+m0];
    float a1 = (m1 < R) ? (k0*Ksm[m1] + k1*Ksm[R+m1] + k2*Ksm[2*R+m1]) : -1e30f;
    float mx = wmaxr(fmaxf(a0, a1));
    float e0 = __expf(a0 - mx);
    float e1 = (m1 < R) ? __expf(a1 - mx) : 0.f;
    float sm = wsum(e0 + e1);
    float sab = wsum(e0 * ab2l[m0] + ((m1 < R) ? e1 * ab2l[m1] : 0.f));
    float inv = 1.f / sm;
    bA[n*LS + m0] = f2bf(e0 * inv);
    if (m1 < R) bA[n*LS + m1] = f2bf(e1 * inv);
    if (lane == 0) ssm[n] = sab * inv;
  }
  __syncthreads();

  // ---- Stage A: W = P @ aw2 -> bB ----
  {
    f32x4 acc[4];
    #pragma unroll
    for (int t = 0; t < 4; t++) acc[t] = vzero;
    for (int kk = 0; kk < 128; kk += 32){
      bf16x8 a = *(const bf16x8*)&bA[(tr*16 + qm)*LS + kk + quad*8];
      #pragma unroll
      for (int t = 0; t < 4; t++){
        int n = (tc0 + t)*16 + qm;
        bf16x8 bf = *(const bf16x8*)(aw2l + n*128 + kk + quad*8);
        acc[t] = __builtin_amdgcn_mfma_f32_16x16x32_bf16(a, bf, acc[t], 0, 0, 0);
      }
    }
    #pragma unroll
    for (int t = 0; t < 4; t++){
      int n = (tc0 + t)*16 + qm;
      #pragma unroll
      for (int rg = 0; rg < 4; rg++)
        bB[(tr*16 + quad*4 + rg)*LS + n] = f2bf(acc[t][rg]);
    }
  }
  __syncthreads();

  // ---- Stage B: M = Z @ W^T + ssm -> bA ----
  {
    f32x4 acc[4];
    #pragma unroll
    for (int t = 0; t < 4; t++) acc[t] = vzero;
    for (int kk = 0; kk < 128; kk += 32){
      bf16x8 a = *(const bf16x8*)&Zl[(tr*16 + qm)*LS + kk + quad*8];
      #pragma unroll
      for (int t = 0; t < 4; t++){
        int n = (tc0 + t)*16 + qm;
        bf16x8 bf = *(const bf16x8*)&bB[n*LS + kk + quad*8];
        acc[t] = __builtin_amdgcn_mfma_f32_16x16x32_bf16(a, bf, acc[t], 0, 0, 0);
      }
    }
    #pragma unroll
    for (int t = 0; t < 4; t++){
      int n = (tc0 + t)*16 + qm;
      float sadd = (n < R) ? ssm[n] : 0.f;
      #pragma unroll
      for (int rg = 0; rg < 4; rg++)
        bA[(tr*16 + quad*4 + rg)*LS + n] = f2bf(acc[t][rg] + sadd);
    }
  }
  __syncthreads();

  // ---- Stage C: T1 = M @ Z -> bB ----
  {
    f32x4 acc[4];
    #pragma unroll
    for (int t = 0; t < 4; t++) acc[t] = vzero;
    for (int kk = 0; kk < 128; kk += 32){
      bf16x8 a = *(const bf16x8*)&bA[(tr*16 + qm)*LS + kk + quad*8];
      #pragma unroll
      for (int t = 0; t < 4; t++){
        int n = (tc0 + t)*16 + qm;
        bf16x8 bf = *(const bf16x8*)&ZTl[n*LS + kk + quad*8];
        acc[t] = __builtin_amdgcn_mfma_f32_16x16x32_bf16(a, bf, acc[t], 0, 0, 0);
      }
    }
    #pragma unroll
    for (int t = 0; t < 4; t++){
      int n = (tc0 + t)*16 + qm;
      #pragma unroll
      for (int rg = 0; rg < 4; rg++)
        bB[(tr*16 + quad*4 + rg)*LS + n] = f2bf(acc[t][rg]);
    }
  }
  __syncthreads();

  // ---- Stage D: Z1 = T1 @ ew^T + eb -> global bf16; row stats -> LDS partials ----
  {
    f32x4 acc[4];
    #pragma unroll
    for (int t = 0; t < 4; t++) acc[t] = vzero;
    for (int kk = 0; kk < 128; kk += 32){
      bf16x8 a = *(const bf16x8*)&bB[(tr*16 + qm)*LS + kk + quad*8];
      #pragma unroll
      for (int t = 0; t < 4; t++){
        int n = (tc0 + t)*16 + qm;
        bf16x8 bf = *(const bf16x8*)(ewl + n*128 + kk + quad*8);
        acc[t] = __builtin_amdgcn_mfma_f32_16x16x32_bf16(a, bf, acc[t], 0, 0, 0);
      }
    }
    float ssv[4] = {0.f,0.f,0.f,0.f}, sqv[4] = {0.f,0.f,0.f,0.f};
    #pragma unroll
    for (int t = 0; t < 4; t++){
      int col = (tc0 + t)*16 + qm;
      float bias = (col < R) ? ebl[col] : 0.f;
      #pragma unroll
      for (int rg = 0; rg < 4; rg++){
        int row = tr*16 + quad*4 + rg;
        float v = (col < R) ? (acc[t][rg] + bias) : 0.f;
        if (col < R && row < R)
          Z1[(size_t)b*RR2 + row*R + col] = f2bf(v);
        ssv[rg] += v; sqv[rg] += v*v;
      }
    }
    #pragma unroll
    for (int off = 1; off < 16; off <<= 1){
      #pragma unroll
      for (int rg = 0; rg < 4; rg++){
        ssv[rg] += __shfl_xor(ssv[rg], off, 64);
        sqv[rg] += __shfl_xor(sqv[rg], off, 64);
      }
    }
    if (qm == 0){
      int half = wave >> 3;
      #pragma unroll
      for (int rg = 0; rg < 4; rg++){
        int row = tr*16 + quad*4 + rg;
        zps[row*2 + half] = ssv[rg];
        zpq[row*2 + half] = sqv[rg];
      }
    }
  }

  // ---- X path partials: T1x = M @ X (M stable in bA) ----
  if (tid < R*4){
    int n = tid >> 2, part = tid & 3;
    float t0 = 0.f, t1 = 0.f, t2 = 0.f;
    for (int m = part; m < R; m += 4){
      float p = bf2f(bA[n*LS + m]);
      const float* xr = Xb + m*3;
      t0 += p*xr[0]; t1 += p*xr[1]; t2 += p*xr[2];
    }
    xp[tid*3+0] = t0; xp[tid*3+1] = t1; xp[tid*3+2] = t2;
  }
  __syncthreads();
  if (tid < R){
    float c0 = xp[tid*12+0] + xp[tid*12+3] + xp[tid*12+6] + xp[tid*12+9];
    float c1 = xp[tid*12+1] + xp[tid*12+4] + xp[tid*12+7] + xp[tid*12+10];
    float c2 = xp[tid*12+2] + xp[tid*12+5] + xp[tid*12+8] + xp[tid*12+11];
    float s = 0.f, q = 0.f;
    #pragma unroll
    for (int e = 0; e < 3; e++){
      float v = nbl[e] + c0*nwl[e*3+0] + c1*nwl[e*3+1] + c2*nwl[e*3+2];
      X1[((size_t)b*R + tid)*3 + e] = v;
      s += v; q += v*v;
    }
    // one atomic per row per block, sharded 8 ways (tail; no barrier after)
    int sh = b & (NSH-1);
    atomicAdd(&xsumS[sh*STL + layer*R + tid], s);
    atomicAdd(&xsqS [sh*STL + layer*R + tid], q);
    atomicAdd(&zsumS[sh*STL + layer*R + tid], zps[tid*2] + zps[tid*2+1]);
    atomicAdd(&zsqS [sh*STL + layer*R + tid], zpq[tid*2] + zpq[tid*2+1]);
  }
}

// ---------------- fused: BN+relu+residual on Z, then edge downsample ----------------
__launch_bounds__(256)
__global__ void k_bnzde(const ushort_t* __restrict__ Z1, ushort_t* __restrict__ Zc,
                        const float* __restrict__ zsumS, const float* __restrict__ zsqS,
                        const float* __restrict__ geg, const float* __restrict__ geb,
                        const float* __restrict__ dew, const float* __restrict__ deb,
                        ushort_t* __restrict__ XZ, float* __restrict__ deS, int layer)
{
  __shared__ float rb[64*121];
  __shared__ float wsm[78];
  __shared__ float reds[4], redq[4];
  const int tid = threadIdx.x;
  const int gr0 = blockIdx.x * 64;
  const int t = layer + 1;
  if (tid < 78) wsm[tid] = dew[t*78 + tid];
  const int row = tid >> 2, part = tid & 3;
  const int gr = gr0 + row;
  const int n = gr % R;
  const float cnt = (float)(BATCH * R);
  float ms = 0.f, qs = 0.f;
  #pragma unroll
  for (int s2 = 0; s2 < NSH; s2++){
    ms += zsumS[s2*STL + layer*R + n];
    qs += zsqS [s2*STL + layer*R + n];
  }
  float m  = ms / cnt;
  float va = fmaxf(qs / cnt - m*m, 0.f);
  float rs = rsqrtf(va + EPSF);
  float g  = geg[layer*R + n], be = geb[layer*R + n];
  const ushort_t* z1r = Z1 + (size_t)gr * R;
  ushort_t* zcr = Zc + (size_t)gr * R;
  #pragma unroll 4
  for (int i = 0; i < 29; i++){
    int c = part*29 + i;
    float val = fmaxf((bf2f(z1r[c]) - m)*rs*g + be, 0.f) + bf2f(zcr[c]);
    zcr[c] = f2bf(val);
    rb[row*121 + c] = val;
  }
  __syncthreads();
  int jlo = (part == 0) ? 39 : 0;
  int jhi = (part == 2) ? 77 : 78;
  if (part == 3){ jlo = 0; jhi = 0; }
  int off = (part - 1) * 39;
  float f = 0.f;
  for (int j = jlo; j < jhi; j++) f += wsm[j] * rb[row*121 + j + off];
  float s = 0.f, q = 0.f;
  if (part < 3){
    f = fmaxf(f + deb[t], 0.f);
    int bi = gr / R, r = gr - bi*R;
    XZ[(size_t)bi*XZS + 5*R + t*3*R + r*3 + part] = f2bf(f);
    s = f; q = f*f;
  }
  s = wsum(s); q = wsum(q);
  int lane = tid & 63, wv = tid >> 6;
  if (lane == 0){ reds[wv] = s; redq[wv] = q; }
  __syncthreads();
  if (tid == 0){
    atomicAdd(&deS[t*2+0], reds[0]+reds[1]+reds[2]+reds[3]);
    atomicAdd(&deS[t*2+1], redq[0]+redq[1]+redq[2]+redq[3]);
  }
}

// ---------------- fused: BN+relu+residual on X, then node downsample ----------------
__global__ void k_bnxdn(const float* __restrict__ X1, float* __restrict__ Xc,
                        const float* __restrict__ xsumS, const float* __restrict__ xsqS,
                        const float* __restrict__ gng, const float* __restrict__ gnb,
                        const float* __restrict__ dnw, const float* __restrict__ dnb,
                        ushort_t* __restrict__ XZ, float* __restrict__ dnS, int layer)
{
  int idx = blockIdx.x * 256 + threadIdx.x;    // BATCH*R
  int n = idx % R;
  const int t = layer + 1;
  const float cnt = (float)(BATCH * 3);
  float ms = 0.f, qs = 0.f;
  #pragma unroll
  for (int s2 = 0; s2 < NSH; s2++){
    ms += xsumS[s2*STL + layer*R + n];
    qs += xsqS [s2*STL + layer*R + n];
  }
  float m  = ms / cnt;
  float va = fmaxf(qs / cnt - m*m, 0.f);
  float rs = rsqrtf(va + EPSF);
  float g  = gng[layer*R + n], be = gnb[layer*R + n];
  float v[3];
  #pragma unroll
  for (int c = 0; c < 3; c++){
    float x = (X1[idx*3 + c] - m)*rs*g + be;
    v[c] = fmaxf(x, 0.f) + Xc[idx*3 + c];
    Xc[idx*3 + c] = v[c];
  }
  float f = fmaxf(dnw[t*3+0]*v[0] + dnw[t*3+1]*v[1] + dnw[t*3+2]*v[2] + dnb[t], 0.f);
  int bi = idx / R, r = idx - bi*R;
  XZ[(size_t)bi*XZS + t*R + r] = f2bf(f);
  float s = wsum(f), q = wsum(f*f);
  __shared__ float s1[4], s2m[4];
  int lane = threadIdx.x & 63, wv = threadIdx.x >> 6;
  if (lane == 0){ s1[wv] = s; s2m[wv] = q; }
  __syncthreads();
  if (threadIdx.x == 0){
    atomicAdd(&dnS[t*2+0], s1[0]+s1[1]+s1[2]+s1[3]);
    atomicAdd(&dnS[t*2+1], s2m[0]+s2m[1]+s2m[2]+s2m[3]);
  }
}

// ---------------- t=0 node downsample ----------------
__global__ void k_dnode0(const float* __restrict__ Xc, const float* __restrict__ dnw,
                         const float* __restrict__ dnb, ushort_t* __restrict__ XZ,
                         float* __restrict__ dnS){
  int idx = blockIdx.x * 256 + threadIdx.x;    // BATCH*R
  float f = fmaxf(dnw[0]*Xc[idx*3] + dnw[1]*Xc[idx*3+1] + dnw[2]*Xc[idx*3+2] + dnb[0], 0.f);
  int bi = idx / R, r = idx - bi*R;
  XZ[(size_t)bi*XZS + r] = f2bf(f);
  float s = wsum(f), q = wsum(f*f);
  __shared__ float s1[4], s2[4];
  int lane = threadIdx.x & 63, wv = threadIdx.x >> 6;
  if (lane == 0){ s1[wv] = s; s2[wv] = q; }
  __syncthreads();
  if (threadIdx.x == 0){
    atomicAdd(&dnS[0], s1[0]+s1[1]+s1[2]+s1[3]);
    atomicAdd(&dnS[1], s2[0]+s2[1]+s2[2]+s2[3]);
  }
}

// ---------------- t=0 edge downsample ----------------
__global__ void k_dedge0(const ushort_t* __restrict__ Zc, const float* __restrict__ dew,
                         const float* __restrict__ deb, ushort_t* __restrict__ XZ,
                         float* __restrict__ deS){
  __shared__ float wsm[78];
  if (threadIdx.x < 78) wsm[threadIdx.x] = dew[threadIdx.x];
  __syncthreads();
  int idx = blockIdx.x * 256 + threadIdx.x;    // BATCH*R
  const ushort_t* x = Zc + (size_t)idx * R;
  float bb = deb[0];
  float f0 = 0.f, f1 = 0.f, f2 = 0.f;
  for (int j = 0; j < 78; j++){
    float w = wsm[j];
    if (j >= 39) f0 += w * bf2f(x[j - 39]);
    f1 += w * bf2f(x[j]);
    if (j < 77)  f2 += w * bf2f(x[j + 39]);
  }
  f0 = fmaxf(f0 + bb, 0.f); f1 = fmaxf(f1 + bb, 0.f); f2 = fmaxf(f2 + bb, 0.f);
  int bi = idx / R, r = idx - bi*R;
  size_t base = (size_t)bi*XZS + 5*R + r*3;
  XZ[base+0] = f2bf(f0); XZ[base+1] = f2bf(f1); XZ[base+2] = f2bf(f2);
  float s = wsum(f0+f1+f2), q = wsum(f0*f0+f1*f1+f2*f2);
  __shared__ float s1[4], s2[4];
  int lane = threadIdx.x & 63, wv = threadIdx.x >> 6;
  if (lane == 0){ s1[wv] = s; s2[wv] = q; }
  __syncthreads();
  if (threadIdx.x == 0){
    atomicAdd(&deS[0], s1[0]+s1[1]+s1[2]+s1[3]);
    atomicAdd(&deS[1], s2[0]+s2[1]+s2[2]+s2[3]);
  }
}

// ---------------- apply BN (in place) to XZ feature slots for snapshot t ----------------
__global__ void k_apply(const float* __restrict__ dnS, const float* __restrict__ deS,
                        const float* __restrict__ dng, const float* __restrict__ dnbe,
                        const float* __restrict__ deg, const float* __restrict__ debe,
                        ushort_t* __restrict__ XZ, int t)
{
  int idx = blockIdx.x * 256 + threadIdx.x;    // BATCH*R
  int bi = idx / R, r = idx - bi*R;
  const float cn = (float)(BATCH * R);
  float mn = dnS[t*2+0] / cn;
  float vn = fmaxf(dnS[t*2+1] / cn - mn*mn, 0.f);
  size_t sn = (size_t)bi*XZS + t*R + r;
  float hn = (bf2f(XZ[sn]) - mn) * rsqrtf(vn + EPSF) * dng[t] + dnbe[t];
  XZ[sn] = f2bf(hn);
  const float ce = (float)(BATCH * R * 3);
  float me = deS[t*2+0] / ce;
  float ve = fmaxf(deS[t*2+1] / ce - me*me, 0.f);
  float rse = rsqrtf(ve + EPSF);
  size_t se = (size_t)bi*XZS + 5*R + t*3*R + r*3;
  #pragma unroll
  for (int p = 0; p < 3; p++){
    float he = (bf2f(XZ[se+p]) - me) * rse * deg[t] + debe[t];
    XZ[se+p] = f2bf(he);
  }
}

// ---------------- classifier: fc1 bf16 MFMA GEMM ----------------
__launch_bounds__(256)
__global__ void k_fc1(const ushort_t* __restrict__ XZ, const ushort_t* __restrict__ cw1p,
                      const float* __restrict__ cb1, float* __restrict__ H){
  const int tid  = threadIdx.x;
  const int lane = tid & 63;
  const int wave = tid >> 6;
  const int qm   = lane & 15;
  const int quad = lane >> 4;
  const int m0   = blockIdx.x * 64 + wave * 16;
  const int n0   = blockIdx.y * 64;

  const f32x4 vzero = {0.f, 0.f, 0.f, 0.f};
  f32x4 acc[4];
  #pragma unroll
  for (int t = 0; t < 4; t++) acc[t] = vzero;

  const ushort_t* arow = XZ + (size_t)(m0 + qm) * XZS;
  for (int kk = 0; kk < XZS; kk += 32){
    bf16x8 a = *(const bf16x8*)(arow + kk + quad*8);
    #pragma unroll
    for (int t = 0; t < 4; t++){
      const ushort_t* brow = cw1p + (size_t)(n0 + t*16 + qm) * XZS;
      bf16x8 bf = *(const bf16x8*)(brow + kk + quad*8);
      acc[t] = __builtin_amdgcn_mfma_f32_16x16x32_bf16(a, bf, acc[t], 0, 0, 0);
    }
  }
  #pragma unroll
  for (int t = 0; t < 4; t++){
    int n = n0 + t*16 + qm;
    float bias = cb1[n];
    #pragma unroll
    for (int rg = 0; rg < 4; rg++){
      int m = m0 + quad*4 + rg;
      H[(size_t)m * 1024 + n] = fmaxf(acc[t][rg] + bias, 0.f);
    }
  }
}

__global__ void k_fc2(const float* __restrict__ H, const float* __restrict__ cw2,
                      const float* __restrict__ cb2, float* __restrict__ out){
  int b = blockIdx.x, tid = threadIdx.x;
  float a0 = 0.f, a1 = 0.f;
  for (int j = tid; j < 1024; j += 256){
    float h = H[(size_t)b * 1024 + j];
    a0 += h * cw2[j];
    a1 += h * cw2[1024 + j];
  }
  a0 = wsum(a0); a1 = wsum(a1);
  __shared__ float s0[4], s1[4];
  int lane = tid & 63, wave = tid >> 6;
  if (lane == 0){ s0[wave] = a0; s1[wave] = a1; }
  __syncthreads();
  if (tid == 0){
    out[b*2 + 0] = s0[0]+s0[1]+s0[2]+s0[3] + cb2[0];
    out[b*2 + 1] = s1[0]+s1[1]+s1[2]+s1[3] + cb2[1];
  }
}

extern "C" void kernel_launch(void* const* d_in, const int* in_sizes, int n_in,
                              void* d_out, int out_size, void* d_ws, size_t ws_size,
                              hipStream_t stream)
{
  const float* Xin  = (const float*)d_in[0];
  const float* Zin  = (const float*)d_in[1];
  const float* aw1  = (const float*)d_in[2];
  const float* ab1  = (const float*)d_in[3];
  const float* aw2  = (const float*)d_in[4];
  const float* ab2  = (const float*)d_in[5];
  const float* nw   = (const float*)d_in[6];
  const float* nb   = (const float*)d_in[7];
  const float* ew   = (const float*)d_in[8];
  const float* eb   = (const float*)d_in[9];
  const float* gng  = (const float*)d_in[10];
  const float* gnb  = (const float*)d_in[11];
  const float* geg  = (const float*)d_in[12];
  const float* geb  = (const float*)d_in[13];
  const float* dnw  = (const float*)d_in[14];
  const float* dnb  = (const float*)d_in[15];
  const float* dng  = (const float*)d_in[16];
  const float* dnbe = (const float*)d_in[17];
  const float* dew  = (const float*)d_in[18];
  const float* deb  = (const float*)d_in[19];
  const float* deg  = (const float*)d_in[20];
  const float* debe = (const float*)d_in[21];
  const float* cw1  = (const float*)d_in[22];
  const float* cb1  = (const float*)d_in[23];
  const float* cw2  = (const float*)d_in[24];
  const float* cb2  = (const float*)d_in[25];

  // ---- workspace layout: TOTAL 67,856,512 B < 69,605,444 B (proven addressable, R3) ----
  ushort_t* Zc = (ushort_t*)d_ws;            // bf16 Z state
  ushort_t* Z1 = Zc + NZ_ELEM;               // bf16 pre-BN Z1
  float*    H  = (float*)Z1;                 //   overlay: fc1 out (Z1 dead at fc1)
  float*    Xc = (float*)(Z1 + NZ_ELEM);     // fp32 X state
  float*    X1 = Xc + NX_ELEM;               // fp32 pre-BN X1
  ushort_t* XZ = (ushort_t*)(X1 + NX_ELEM);  // bf16 features (B,XZS)
  float*    st = (float*)(XZ + BATCH*XZS);   // stats: 14880 floats (sharded)
  ushort_t* aw2p = (ushort_t*)(st + 14880);
  ushort_t* ewp  = aw2p + 4*16384;
  ushort_t* cw1p = ewp + 4*16384;
  float* zsumS = st;               // [NSH][STL]
  float* zsqS  = st + 3712;
  float* xsumS = st + 7424;
  float* xsqS  = st + 11136;
  float* dnS   = st + 14848;       // [5][2]
  float* deS   = st + 14858;

  float* outp = (float*)d_out;

  // init
  k_initZ<<<2048, 256, 0, stream>>>((const float4*)Zin, (uint4*)Zc, NZ_ELEM / 8);
  k_initX<<<1392, 256, 0, stream>>>(Xin, Xc, NX_ELEM, st, 14880,
                                    (unsigned*)XZ, BATCH*XZS/2);
  k_initW<<<256, 256, 0, stream>>>(aw2, ew, aw2p, ewp);
  k_initC<<<9344, 256, 0, stream>>>(cw1, cw1p);

  // t = 0 snapshots
  k_dnode0<<<464, 256, 0, stream>>>(Xc, dnw, dnb, XZ, dnS);
  k_dedge0<<<464, 256, 0, stream>>>(Zc, dew, deb, XZ, deS);
  k_apply<<<464, 256, 0, stream>>>(dnS, deS, dng, dnbe, deg, debe, XZ, 0);

  for (int i = 0; i < NL; i++){
    k_attn<<<BATCH, 1024, 0, stream>>>(Xc, Zc, Z1, X1, aw1, ab1, aw2p, ab2,
                                       nw, nb, ewp, eb, zsumS, zsqS, xsumS, xsqS, i);
    k_bnzde<<<1856, 256, 0, stream>>>(Z1, Zc, zsumS, zsqS, geg, geb,
                                      dew, deb, XZ, deS, i);
    k_bnxdn<<<464, 256, 0, stream>>>(X1, Xc, xsumS, xsqS, gng, gnb,
                                     dnw, dnb, XZ, dnS, i);
    k_apply<<<464, 256, 0, stream>>>(dnS, deS, dng, dnbe, deg, debe, XZ, i + 1);
  }

  k_fc1<<<dim3(16, 16), 256, 0, stream>>>(XZ, cw1p, cb1, H);
  k_fc2<<<BATCH, 256, 0, stream>>>(H, cw2, cb2, outp);
}